// Round 11
// baseline (275.886 us; speedup 1.0000x reference)
//
#include <hip/hip_runtime.h>

#define BB   16384
#define GENC 216
#define OBS  512
#define NH   1024
#define NC   64
#define NFAC 8
#define NIN  1240
#define KP1  1280   // layer-1 K padded to multiple of 64
#define MTILES 136  // worst-case sum ceil(cnt_f/128)

typedef __attribute__((ext_vector_type(4))) float f32x4;
typedef __attribute__((ext_vector_type(8))) short short8;
typedef __attribute__((ext_vector_type(4))) short short4v;

__device__ __forceinline__ unsigned short f2bf(float f) {
  union { float f; unsigned u; } x; x.f = f;
  unsigned r = x.u + 0x7fffu + ((x.u >> 16) & 1u);
  return (unsigned short)(r >> 16);
}

__device__ __forceinline__ void gl_lds16(const unsigned short* g, unsigned short* l) {
  __builtin_amdgcn_global_load_lds(
      (const __attribute__((address_space(1))) void*)g,
      (__attribute__((address_space(3))) void*)l, 16, 0, 0);
}

// bijective XCD-chunked swizzle (m204)
__device__ __forceinline__ int xcd_chunk(int gid, int nwg) {
  int q = nwg >> 3, r = nwg & 7, x = gid & 7, p = gid >> 3;
  return (x < r ? x * (q + 1) : r * (q + 1) + (x - r) * q) + p;
}

// ---------- bucket: per-row last-active factor, LDS-aggregated atomics ----------
__global__ void bucket_kernel(const float* __restrict__ graph,
                              int* __restrict__ cnt, int* __restrict__ rowlist) {
  __shared__ int lcnt[NFAC];
  __shared__ int lbase[NFAC];
  int tid = threadIdx.x;
  if (tid < NFAC) lcnt[tid] = 0;
  __syncthreads();
  int b = blockIdx.x * 256 + tid;
  const float* g = graph + (size_t)b * GENC;
  float4 g0 = *(const float4*)g;
  float4 g1 = *(const float4*)(g + 4);
  int f = -1;
  if (g0.x == 1.f) f = 0;
  if (g0.y == 1.f) f = 1;
  if (g0.z == 1.f) f = 2;
  if (g0.w == 1.f) f = 3;
  if (g1.x == 1.f) f = 4;
  if (g1.y == 1.f) f = 5;
  if (g1.z == 1.f) f = 6;
  if (g1.w == 1.f) f = 7;
  int li = 0;
  if (f >= 0) li = atomicAdd(&lcnt[f], 1);
  __syncthreads();
  if (tid < NFAC) lbase[tid] = lcnt[tid] ? atomicAdd(&cnt[tid], lcnt[tid]) : 0;
  __syncthreads();
  if (f >= 0) rowlist[f * BB + lbase[f] + li] = b;
}

// -------- gather active rows (global position), concat + f32->bf16, pad to 1280 --------
__global__ void gather_x(const float* __restrict__ graph,
                         const float* __restrict__ state,
                         const float* __restrict__ nexts,
                         const int* __restrict__ cnt,
                         const int* __restrict__ rowlist,
                         unsigned short* __restrict__ xg) {
  int w = threadIdx.x >> 6, lane = threadIdx.x & 63;
  int pos = blockIdx.x * 4 + w;
  int f = -1, loc = 0, acc = 0;
#pragma unroll
  for (int i = 0; i < NFAC; ++i) {
    int c = cnt[i];
    if (f < 0 && pos < acc + c) { f = i; loc = pos - acc; }
    acc += c;
  }
  if (f < 0) return;
  int b = rowlist[f * BB + loc];
  unsigned short* dst = xg + (size_t)pos * KP1;
#pragma unroll
  for (int it = 0; it < 5; ++it) {
    int c = it * 64 + lane;
    float4 v;
    if (c < 54)       v = *(const float4*)(graph + (size_t)b * GENC + c * 4);
    else if (c < 182) v = *(const float4*)(state + (size_t)b * OBS + (c - 54) * 4);
    else if (c < 310) v = *(const float4*)(nexts + (size_t)b * OBS + (c - 182) * 4);
    else              v = make_float4(0.f, 0.f, 0.f, 0.f);
    short4v s;
    s[0] = (short)f2bf(v.x); s[1] = (short)f2bf(v.y);
    s[2] = (short)f2bf(v.z); s[3] = (short)f2bf(v.w);
    *(short4v*)(dst + c * 4) = s;
  }
}

// ---- merged transpose+convert: f32 [F][K][N] -> bf16 [F][N][KPad] ----
__global__ void transpose_all(const float* __restrict__ W1,
                              const float* __restrict__ W2,
                              const float* __restrict__ W3,
                              unsigned short* __restrict__ w1t,
                              unsigned short* __restrict__ w2t,
                              unsigned short* __restrict__ w3t) {
  __shared__ unsigned short tile[64][65];
  int z = blockIdx.z;
  const float* src; unsigned short* dst; int K, N, KPad;
  if (z < 8)        { src = W1 + (size_t)z * NIN * NH;       dst = w1t + (size_t)z * NH * KP1; K = NIN; N = NH; KPad = KP1; }
  else if (z < 16)  { src = W2 + (size_t)(z - 8) * NH * NH;  dst = w2t + (size_t)(z - 8) * NH * NH; K = NH; N = NH; KPad = NH; }
  else              { src = W3 + (size_t)(z - 16) * NH * NC; dst = w3t + (size_t)(z - 16) * NC * NH; K = NH; N = NC; KPad = NH; }
  int k0 = blockIdx.y * 64, n0 = blockIdx.x * 64;
  if (k0 >= KPad || n0 >= N) return;
  int tr = threadIdx.x >> 6, tc = threadIdx.x & 63;
#pragma unroll
  for (int i = 0; i < 16; ++i) {
    int r = i * 4 + tr;
    int k = k0 + r;
    float v = (k < K) ? src[(size_t)k * N + n0 + tc] : 0.0f;
    tile[r][tc] = f2bf(v);
  }
  __syncthreads();
  int kp = threadIdx.x & 31, nb = threadIdx.x >> 5;
#pragma unroll
  for (int i = 0; i < 8; ++i) {
    int n = i * 8 + nb;
    union { short2 s2; unsigned u; } v;
    v.s2.x = (short)tile[kp * 2][n];
    v.s2.y = (short)tile[kp * 2 + 1][n];
    *(unsigned*)(dst + (size_t)(n0 + n) * KPad + k0 + kp * 2) = v.u;
  }
}

// ====== L1/L2 GEMM: 128x512 tile, 8 waves (1Mx8N), per-wave 128x64 out ======
// LDS 160KB dbuf (2 x {A 16KB, B 64KB}). One vmcnt(0)+barrier per K-tile,
// then FREE-RUNNING sub-phases: {ds A-lo+B, stage 6, MFMA q0(16)},
// {ds A-hi, stage 4, MFMA q1-q3(48)}. Cross-wave slip gives MFMA||ds overlap.
template <int LAYER>
__launch_bounds__(512, 2)
__global__ void mlp_gemm_big(const unsigned short* __restrict__ Abase,
                             const unsigned short* __restrict__ Wt,
                             const float* __restrict__ bias,
                             unsigned short* __restrict__ Hout,
                             const int* __restrict__ cnt) {
  constexpr int K  = (LAYER == 1) ? KP1 : NH;
  constexpr int NT = K / 64;
  constexpr int NB = NH / 512;  // 2 n-blocks

  extern __shared__ unsigned short smem[];

  const int wg = xcd_chunk(blockIdx.x, MTILES * NB);
  const int ty = wg / NB;           // m-tile; n fastest (A-panel L2 reuse)
  const int n0 = (wg % NB) * 512;

  int f = -1, m0 = 0, goff = 0, cntf = 0;
  {
    int acc = 0, off = 0;
#pragma unroll
    for (int i = 0; i < NFAC; ++i) {
      int c = cnt[i];
      int t = (c + 127) >> 7;
      if (f < 0 && ty < acc + t) { f = i; m0 = (ty - acc) * 128; goff = off; cntf = c; }
      acc += t; off += c;
    }
  }
  if (f < 0) return;

  const int tid = threadIdx.x, wid = tid >> 6, lane = tid & 63;

  // staging: per-lane pre-swizzled source, linear LDS dest (rule 21)
  const int sr = tid >> 3;              // row within 64-row unit
  const int sc = (tid & 7) ^ (sr & 7);  // swizzled 16B chunk
  const unsigned short* pA[2];
  const unsigned short* pB[8];
  {
    const unsigned short* Ao = Abase + (size_t)(goff + m0) * K;
    const unsigned short* Bo = Wt + (size_t)f * NH * K + (size_t)n0 * K;
    pA[0] = Ao + (size_t)sr * K + sc * 8;
    pA[1] = Ao + (size_t)(64 + sr) * K + sc * 8;
#pragma unroll
    for (int u = 0; u < 8; ++u) pB[u] = Bo + (size_t)(u * 64 + sr) * K + sc * 8;
  }
  const int dst8 = tid * 8;  // linear elem offset within an 8KB unit

  // buffer layout (elems): buf b at b*40960: A[128][64] then B[512][64]
  f32x4 acc[8][4];
#pragma unroll
  for (int a = 0; a < 8; ++a)
#pragma unroll
    for (int b = 0; b < 4; ++b) acc[a][b] = (f32x4){0.f, 0.f, 0.f, 0.f};

  auto stageA = [&](unsigned short* Ab) {
    gl_lds16(pA[0], Ab + dst8);        pA[0] += 64;
    gl_lds16(pA[1], Ab + 4096 + dst8); pA[1] += 64;
  };
  auto stageB1 = [&](unsigned short* Bb) {
#pragma unroll
    for (int u = 0; u < 4; ++u) { gl_lds16(pB[u], Bb + u * 4096 + dst8); pB[u] += 64; }
  };
  auto stageB2 = [&](unsigned short* Bb) {
#pragma unroll
    for (int u = 4; u < 8; ++u) { gl_lds16(pB[u], Bb + u * 4096 + dst8); pB[u] += 64; }
  };

  // prologue: tile 0 fully staged (10 loads/thread in flight)
  stageA(smem);
  stageB1(smem + 8192);
  stageB2(smem + 8192);

#pragma unroll 1
  for (int t = 0; t < NT; ++t) {
    unsigned short* Ab = smem + (t & 1) * 40960;
    unsigned short* Bb = Ab + 8192;
    unsigned short* An = smem + ((t & 1) ^ 1) * 40960;
    unsigned short* Bn = An + 8192;

    asm volatile("s_waitcnt vmcnt(0)" ::: "memory");  // tile t resident (per-wave)
    __builtin_amdgcn_sched_barrier(0);
    __builtin_amdgcn_s_barrier();                     // all waves resident + done w/ buf^1
    __builtin_amdgcn_sched_barrier(0);

    short8 alo[4][2], ahi[4][2], b0[2][2], b1[2][2];
#pragma unroll
    for (int mf = 0; mf < 4; ++mf) {
      int r = mf * 16 + (lane & 15);
#pragma unroll
      for (int ks = 0; ks < 2; ++ks) {
        int kc = ks * 4 + (lane >> 4);
        alo[mf][ks] = *(const short8*)(Ab + r * 64 + ((kc ^ (r & 7)) << 3));
      }
    }
#pragma unroll
    for (int nf = 0; nf < 2; ++nf) {
      int c = wid * 64 + nf * 16 + (lane & 15);
#pragma unroll
      for (int ks = 0; ks < 2; ++ks) {
        int kc = ks * 4 + (lane >> 4);
        b0[nf][ks] = *(const short8*)(Bb + c * 64 + ((kc ^ (c & 7)) << 3));
      }
    }
#pragma unroll
    for (int nf = 0; nf < 2; ++nf) {
      int c = wid * 64 + (nf + 2) * 16 + (lane & 15);
#pragma unroll
      for (int ks = 0; ks < 2; ++ks) {
        int kc = ks * 4 + (lane >> 4);
        b1[nf][ks] = *(const short8*)(Bb + c * 64 + ((kc ^ (c & 7)) << 3));
      }
    }
    if (t + 1 < NT) { stageA(An); stageB1(Bn); }  // 6 loads for t+1

    // q0: A-lo x B-n01
    __builtin_amdgcn_s_setprio(1);
#pragma unroll
    for (int mf = 0; mf < 4; ++mf)
#pragma unroll
      for (int nf = 0; nf < 2; ++nf)
#pragma unroll
        for (int ks = 0; ks < 2; ++ks)
          acc[mf][nf] = __builtin_amdgcn_mfma_f32_16x16x32_bf16(
              alo[mf][ks], b0[nf][ks], acc[mf][nf], 0, 0, 0);
    __builtin_amdgcn_s_setprio(0);

#pragma unroll
    for (int mf = 0; mf < 4; ++mf) {
      int r = (mf + 4) * 16 + (lane & 15);
#pragma unroll
      for (int ks = 0; ks < 2; ++ks) {
        int kc = ks * 4 + (lane >> 4);
        ahi[mf][ks] = *(const short8*)(Ab + r * 64 + ((kc ^ (r & 7)) << 3));
      }
    }
    if (t + 1 < NT) stageB2(Bn);                  // last 4 loads for t+1

    __builtin_amdgcn_s_setprio(1);
    // q1: A-lo x B-n23
#pragma unroll
    for (int mf = 0; mf < 4; ++mf)
#pragma unroll
      for (int nf = 0; nf < 2; ++nf)
#pragma unroll
        for (int ks = 0; ks < 2; ++ks)
          acc[mf][nf + 2] = __builtin_amdgcn_mfma_f32_16x16x32_bf16(
              alo[mf][ks], b1[nf][ks], acc[mf][nf + 2], 0, 0, 0);
    // q2: A-hi x B-n01
#pragma unroll
    for (int mf = 0; mf < 4; ++mf)
#pragma unroll
      for (int nf = 0; nf < 2; ++nf)
#pragma unroll
        for (int ks = 0; ks < 2; ++ks)
          acc[mf + 4][nf] = __builtin_amdgcn_mfma_f32_16x16x32_bf16(
              ahi[mf][ks], b0[nf][ks], acc[mf + 4][nf], 0, 0, 0);
    // q3: A-hi x B-n23
#pragma unroll
    for (int mf = 0; mf < 4; ++mf)
#pragma unroll
      for (int nf = 0; nf < 2; ++nf)
#pragma unroll
        for (int ks = 0; ks < 2; ++ks)
          acc[mf + 4][nf + 2] = __builtin_amdgcn_mfma_f32_16x16x32_bf16(
              ahi[mf][ks], b1[nf][ks], acc[mf + 4][nf + 2], 0, 0, 0);
    __builtin_amdgcn_s_setprio(0);
  }

  // ---- epilogue: bias + relu + bf16 store ----
  const float* bs = bias + f * NH;
#pragma unroll
  for (int nf = 0; nf < 4; ++nf) {
    int col = n0 + wid * 64 + nf * 16 + (lane & 15);
    float bvv = bs[col];
#pragma unroll
    for (int mf = 0; mf < 8; ++mf) {
      int rbase = mf * 16 + ((lane >> 4) << 2);
#pragma unroll
      for (int i = 0; i < 4; ++i) {
        int pos = m0 + rbase + i;
        if (pos < cntf) {
          float v = fmaxf(acc[mf][nf][i] + bvv, 0.0f);
          Hout[(size_t)(goff + pos) * NH + col] = f2bf(v);
        }
      }
    }
  }
}

// ------ layer-3 GEMM: depth-2 counted-vmcnt 128x64 (rowlist scatter epilogue) ------
__launch_bounds__(256, 2)
__global__ void mlp_gemm3(const unsigned short* __restrict__ Abase,
                          const unsigned short* __restrict__ Wt,
                          const float* __restrict__ bias,
                          float* __restrict__ Out,
                          const int* __restrict__ cnt,
                          const int* __restrict__ rowlist) {
  constexpr int K = NH;
  constexpr int NKT = K / 64;

  const int wg = xcd_chunk(blockIdx.x, MTILES);
  const int ty = wg;

  int f = -1, m0 = 0, goff = 0, cntf = 0;
  {
    int acc = 0, off = 0;
#pragma unroll
    for (int i = 0; i < NFAC; ++i) {
      int c = cnt[i];
      int t = (c + 127) >> 7;
      if (f < 0 && ty < acc + t) { f = i; m0 = (ty - acc) * 128; goff = off; cntf = c; }
      acc += t; off += c;
    }
  }
  if (f < 0) return;

  __shared__ unsigned short As[2][128 * 64];
  __shared__ unsigned short Bs[2][64 * 64];

  const int tid = threadIdx.x;
  const int wid = tid >> 6, lane = tid & 63;

  const int rl = lane >> 3;
  const int chs = (lane & 7) ^ rl;
  const unsigned short* pA[4];
  const unsigned short* pB[2];
  {
    const unsigned short* Aorg = Abase + (size_t)(goff + m0) * K;
    const unsigned short* Borg = Wt + (size_t)f * NC * K;
#pragma unroll
    for (int i = 0; i < 4; ++i)
      pA[i] = Aorg + (size_t)(wid * 32 + i * 8 + rl) * K + chs * 8;
#pragma unroll
    for (int i = 0; i < 2; ++i)
      pB[i] = Borg + (size_t)(wid * 16 + i * 8 + rl) * K + chs * 8;
  }

  f32x4 acc[2][4];
#pragma unroll
  for (int a = 0; a < 2; ++a)
#pragma unroll
    for (int b = 0; b < 4; ++b) acc[a][b] = (f32x4){0.f, 0.f, 0.f, 0.f};

  auto stage = [&](int buf) {
#pragma unroll
    for (int i = 0; i < 4; ++i) {
      gl_lds16(pA[i], &As[buf][(wid * 32 + i * 8) * 64]);
      pA[i] += 64;
    }
#pragma unroll
    for (int i = 0; i < 2; ++i) {
      gl_lds16(pB[i], &Bs[buf][(wid * 16 + i * 8) * 64]);
      pB[i] += 64;
    }
  };

  auto compute = [&](int buf) {
#pragma unroll
    for (int ks = 0; ks < 2; ++ks) {
      const int kc8 = ks * 4 + (lane >> 4);
      short8 av[2], bv[4];
#pragma unroll
      for (int mf = 0; mf < 2; ++mf) {
        int row = wid * 32 + mf * 16 + (lane & 15);
        av[mf] = *(const short8*)(&As[buf][0] + row * 64 + ((kc8 ^ (row & 7)) << 3));
      }
#pragma unroll
      for (int nf = 0; nf < 4; ++nf) {
        int col = nf * 16 + (lane & 15);
        bv[nf] = *(const short8*)(&Bs[buf][0] + col * 64 + ((kc8 ^ (col & 7)) << 3));
      }
      __builtin_amdgcn_s_setprio(1);
#pragma unroll
      for (int mf = 0; mf < 2; ++mf)
#pragma unroll
        for (int nf = 0; nf < 4; ++nf)
          acc[mf][nf] = __builtin_amdgcn_mfma_f32_16x16x32_bf16(
              av[mf], bv[nf], acc[mf][nf], 0, 0, 0);
      __builtin_amdgcn_s_setprio(0);
    }
  };

  stage(0);
  stage(1);
#pragma unroll 1
  for (int kt = 0; kt < NKT; ++kt) {
    if (kt < NKT - 1) { asm volatile("s_waitcnt vmcnt(6)" ::: "memory"); }
    else              { asm volatile("s_waitcnt vmcnt(0)" ::: "memory"); }
    __builtin_amdgcn_sched_barrier(0);
    __builtin_amdgcn_s_barrier();
    __builtin_amdgcn_sched_barrier(0);
    compute(kt & 1);
    __builtin_amdgcn_sched_barrier(0);
    __builtin_amdgcn_s_barrier();
    __builtin_amdgcn_sched_barrier(0);
    if (kt + 2 < NKT) stage(kt & 1);
  }

  const float* bs = bias + f * NC;
#pragma unroll
  for (int nf = 0; nf < 4; ++nf) {
    int col = nf * 16 + (lane & 15);
    float bvv = bs[col];
#pragma unroll
    for (int mf = 0; mf < 2; ++mf) {
      int rbase = wid * 32 + mf * 16 + ((lane >> 4) << 2);
#pragma unroll
      for (int i = 0; i < 4; ++i) {
        int pos = m0 + rbase + i;
        if (pos < cntf) {
          int b = rowlist[f * BB + pos];
          Out[(size_t)b * NC + col] = acc[mf][nf][i] + bvv;
        }
      }
    }
  }
}

extern "C" void kernel_launch(void* const* d_in, const int* in_sizes, int n_in,
                              void* d_out, int out_size, void* d_ws, size_t ws_size,
                              hipStream_t stream) {
  const float* graph = (const float*)d_in[0];
  const float* state = (const float*)d_in[1];
  const float* nexts = (const float*)d_in[2];
  const float* W1 = (const float*)d_in[3];
  const float* b1 = (const float*)d_in[4];
  const float* W2 = (const float*)d_in[5];
  const float* b2 = (const float*)d_in[6];
  const float* W3 = (const float*)d_in[7];
  const float* b3 = (const float*)d_in[8];
  float* out = (float*)d_out;
  char* ws = (char*)d_ws;

  const size_t ROWCAP = BB + 256;
  const size_t OFF_ROW = 256;
  const size_t OFF_W1T = OFF_ROW + (size_t)NFAC * BB * 4;
  const size_t OFF_W2T = OFF_W1T + (size_t)NFAC * NH * KP1 * 2;
  const size_t OFF_W3T = OFF_W2T + (size_t)NFAC * NH * NH * 2;
  const size_t OFF_H1  = OFF_W3T + (size_t)NFAC * NC * NH * 2;
  const size_t OFF_XG  = OFF_H1 + ROWCAP * NH * 2;

  int* cnt = (int*)ws;
  int* rowlist = (int*)(ws + OFF_ROW);
  unsigned short* w1t = (unsigned short*)(ws + OFF_W1T);
  unsigned short* w2t = (unsigned short*)(ws + OFF_W2T);
  unsigned short* w3t = (unsigned short*)(ws + OFF_W3T);
  unsigned short* h1  = (unsigned short*)(ws + OFF_H1);
  unsigned short* xg  = (unsigned short*)(ws + OFF_XG);
  unsigned short* h2  = xg;  // reuse: xg dead after layer 1

  hipFuncSetAttribute(reinterpret_cast<const void*>(mlp_gemm_big<1>),
                      hipFuncAttributeMaxDynamicSharedMemorySize, 163840);
  hipFuncSetAttribute(reinterpret_cast<const void*>(mlp_gemm_big<2>),
                      hipFuncAttributeMaxDynamicSharedMemorySize, 163840);

  hipMemsetAsync(cnt, 0, 64, stream);
  hipMemsetAsync(d_out, 0, (size_t)out_size * sizeof(float), stream);

  bucket_kernel<<<BB / 256, 256, 0, stream>>>(graph, cnt, rowlist);
  gather_x<<<BB / 4, 256, 0, stream>>>(graph, state, nexts, cnt, rowlist, xg);
  transpose_all<<<dim3(16, 20, 24), 256, 0, stream>>>(W1, W2, W3, w1t, w2t, w3t);

  mlp_gemm_big<1><<<MTILES * 2, 512, 163840, stream>>>(xg, w1t, b1, h1, cnt);
  mlp_gemm_big<2><<<MTILES * 2, 512, 163840, stream>>>(h1, w2t, b2, h2, cnt);
  mlp_gemm3<<<MTILES, 256, 0, stream>>>(h2, w3t, b3, out, cnt, rowlist);
}

// Round 12
// 264.234 us; speedup vs baseline: 1.0441x; 1.0441x over previous
//
#include <hip/hip_runtime.h>

#define BB   16384
#define GENC 216
#define OBS  512
#define NH   1024
#define NC   64
#define NFAC 8
#define NIN  1240
#define KP1  1280   // layer-1 K padded to multiple of 64
#define MTILES 136  // worst-case sum ceil(cnt_f/128)
#define MT256  72   // worst-case sum ceil(cnt_f/256)

typedef __attribute__((ext_vector_type(4))) float f32x4;
typedef __attribute__((ext_vector_type(8))) short short8;
typedef __attribute__((ext_vector_type(4))) short short4v;

__device__ __forceinline__ unsigned short f2bf(float f) {
  union { float f; unsigned u; } x; x.f = f;
  unsigned r = x.u + 0x7fffu + ((x.u >> 16) & 1u);
  return (unsigned short)(r >> 16);
}

__device__ __forceinline__ void gl_lds16(const unsigned short* g, unsigned short* l) {
  __builtin_amdgcn_global_load_lds(
      (const __attribute__((address_space(1))) void*)g,
      (__attribute__((address_space(3))) void*)l, 16, 0, 0);
}

// bijective XCD-chunked swizzle (m204)
__device__ __forceinline__ int xcd_chunk(int gid, int nwg) {
  int q = nwg >> 3, r = nwg & 7, x = gid & 7, p = gid >> 3;
  return (x < r ? x * (q + 1) : r * (q + 1) + (x - r) * q) + p;
}

// ---------- bucket: per-row last-active factor, LDS-aggregated atomics ----------
__global__ void bucket_kernel(const float* __restrict__ graph,
                              int* __restrict__ cnt, int* __restrict__ rowlist) {
  __shared__ int lcnt[NFAC];
  __shared__ int lbase[NFAC];
  int tid = threadIdx.x;
  if (tid < NFAC) lcnt[tid] = 0;
  __syncthreads();
  int b = blockIdx.x * 256 + tid;
  const float* g = graph + (size_t)b * GENC;
  float4 g0 = *(const float4*)g;
  float4 g1 = *(const float4*)(g + 4);
  int f = -1;
  if (g0.x == 1.f) f = 0;
  if (g0.y == 1.f) f = 1;
  if (g0.z == 1.f) f = 2;
  if (g0.w == 1.f) f = 3;
  if (g1.x == 1.f) f = 4;
  if (g1.y == 1.f) f = 5;
  if (g1.z == 1.f) f = 6;
  if (g1.w == 1.f) f = 7;
  int li = 0;
  if (f >= 0) li = atomicAdd(&lcnt[f], 1);
  __syncthreads();
  if (tid < NFAC) lbase[tid] = lcnt[tid] ? atomicAdd(&cnt[tid], lcnt[tid]) : 0;
  __syncthreads();
  if (f >= 0) rowlist[f * BB + lbase[f] + li] = b;
}

// -------- gather active rows (global position), concat + f32->bf16, pad to 1280 --------
__global__ void gather_x(const float* __restrict__ graph,
                         const float* __restrict__ state,
                         const float* __restrict__ nexts,
                         const int* __restrict__ cnt,
                         const int* __restrict__ rowlist,
                         unsigned short* __restrict__ xg) {
  int w = threadIdx.x >> 6, lane = threadIdx.x & 63;
  int pos = blockIdx.x * 4 + w;
  int f = -1, loc = 0, acc = 0;
#pragma unroll
  for (int i = 0; i < NFAC; ++i) {
    int c = cnt[i];
    if (f < 0 && pos < acc + c) { f = i; loc = pos - acc; }
    acc += c;
  }
  if (f < 0) return;
  int b = rowlist[f * BB + loc];
  unsigned short* dst = xg + (size_t)pos * KP1;
#pragma unroll
  for (int it = 0; it < 5; ++it) {
    int c = it * 64 + lane;
    float4 v;
    if (c < 54)       v = *(const float4*)(graph + (size_t)b * GENC + c * 4);
    else if (c < 182) v = *(const float4*)(state + (size_t)b * OBS + (c - 54) * 4);
    else if (c < 310) v = *(const float4*)(nexts + (size_t)b * OBS + (c - 182) * 4);
    else              v = make_float4(0.f, 0.f, 0.f, 0.f);
    short4v s;
    s[0] = (short)f2bf(v.x); s[1] = (short)f2bf(v.y);
    s[2] = (short)f2bf(v.z); s[3] = (short)f2bf(v.w);
    *(short4v*)(dst + c * 4) = s;
  }
}

// ---- merged transpose+convert: f32 [F][K][N] -> bf16 [F][N][KPad] ----
__global__ void transpose_all(const float* __restrict__ W1,
                              const float* __restrict__ W2,
                              const float* __restrict__ W3,
                              unsigned short* __restrict__ w1t,
                              unsigned short* __restrict__ w2t,
                              unsigned short* __restrict__ w3t) {
  __shared__ unsigned short tile[64][65];
  int z = blockIdx.z;
  const float* src; unsigned short* dst; int K, N, KPad;
  if (z < 8)        { src = W1 + (size_t)z * NIN * NH;       dst = w1t + (size_t)z * NH * KP1; K = NIN; N = NH; KPad = KP1; }
  else if (z < 16)  { src = W2 + (size_t)(z - 8) * NH * NH;  dst = w2t + (size_t)(z - 8) * NH * NH; K = NH; N = NH; KPad = NH; }
  else              { src = W3 + (size_t)(z - 16) * NH * NC; dst = w3t + (size_t)(z - 16) * NC * NH; K = NH; N = NC; KPad = NH; }
  int k0 = blockIdx.y * 64, n0 = blockIdx.x * 64;
  if (k0 >= KPad || n0 >= N) return;
  int tr = threadIdx.x >> 6, tc = threadIdx.x & 63;
#pragma unroll
  for (int i = 0; i < 16; ++i) {
    int r = i * 4 + tr;
    int k = k0 + r;
    float v = (k < K) ? src[(size_t)k * N + n0 + tc] : 0.0f;
    tile[r][tc] = f2bf(v);
  }
  __syncthreads();
  int kp = threadIdx.x & 31, nb = threadIdx.x >> 5;
#pragma unroll
  for (int i = 0; i < 8; ++i) {
    int n = i * 8 + nb;
    union { short2 s2; unsigned u; } v;
    v.s2.x = (short)tile[kp * 2][n];
    v.s2.y = (short)tile[kp * 2 + 1][n];
    *(unsigned*)(dst + (size_t)(n0 + n) * KPad + k0 + kp * 2) = v.u;
  }
}

// ====== m201-style 256x256 8-wave 4-phase-per-K-tile GEMM (L1/L2) ======
// LDS dbuf 2x64KB: A[256][64] + B[256][64] per buf. 8KB units (1 gl_lds/thr).
// Per K-tile t, 4 phases, phase q computes acc frags m={2q,2q+1} x 4n (16 MFMA).
// Stage tile t+1 per phase: q0:B0,B1 q1:B2,B3 q2:A0,A2 q3:A1,A3.
// Waits: end-ph1 vmcnt(4) [tail 0]; end-ph3 vmcnt(2). Never 0 in steady state.
template <int LAYER>
__launch_bounds__(512, 2)
__global__ void mlp_gemm8p(const unsigned short* __restrict__ Abase,
                           const unsigned short* __restrict__ Wt,
                           const float* __restrict__ bias,
                           unsigned short* __restrict__ Hout,
                           const int* __restrict__ cnt) {
  constexpr int K  = (LAYER == 1) ? KP1 : NH;
  constexpr int NT = K / 64;
  constexpr int NB = NH / 256;  // 4 n-blocks

  extern __shared__ unsigned short smem[];

  const int wg = xcd_chunk(blockIdx.x, MT256 * NB);
  const int ty = wg / NB;           // m-tile; n fastest (A-panel L2 reuse)
  const int n0 = (wg % NB) * 256;

  int f = -1, m0 = 0, goff = 0, cntf = 0;
  {
    int acc = 0, off = 0;
#pragma unroll
    for (int i = 0; i < NFAC; ++i) {
      int c = cnt[i];
      int t = (c + 255) >> 8;
      if (f < 0 && ty < acc + t) { f = i; m0 = (ty - acc) * 256; goff = off; cntf = c; }
      acc += t; off += c;
    }
  }
  if (f < 0) return;

  const int tid = threadIdx.x, wid = tid >> 6, lane = tid & 63;
  const int wm = wid >> 2, wn = wid & 3;   // 2M x 4N waves; per-wave out 128x64

  // staging sources: per-lane pre-swizzled (linear LDS dest, swz source)
  const int sr = tid >> 3;              // row within a 64-row unit
  const int sc = (tid & 7) ^ (sr & 7);  // swizzled 16B chunk
  const unsigned short* pu[8];          // 0-3: A units, 4-7: B units
  {
    const unsigned short* Ao = Abase + (size_t)(goff + m0) * K;
    const unsigned short* Bo = Wt + (size_t)f * NH * K + (size_t)n0 * K;
#pragma unroll
    for (int u = 0; u < 4; ++u) pu[u] = Ao + (size_t)(u * 64 + sr) * K + sc * 8;
#pragma unroll
    for (int u = 0; u < 4; ++u) pu[4 + u] = Bo + (size_t)(u * 64 + sr) * K + sc * 8;
  }
  const int dst8 = tid * 8;  // elem offset within a 4096-elem unit

  f32x4 acc[8][4];
#pragma unroll
  for (int a = 0; a < 8; ++a)
#pragma unroll
    for (int b = 0; b < 4; ++b) acc[a][b] = (f32x4){0.f, 0.f, 0.f, 0.f};

  // unit bases: buf(b) A at b*32768 + u*4096; B at b*32768 + 16384 + u*4096
  auto sA = [&](unsigned short* buf, int u) { gl_lds16(pu[u], buf + u * 4096 + dst8); pu[u] += 64; };
  auto sB = [&](unsigned short* buf, int u) { gl_lds16(pu[4 + u], buf + 16384 + u * 4096 + dst8); pu[4 + u] += 64; };

  // prologue: tile 0 -> buf0, order B0,B1,B2,B3,A0,A2,A1,A3
  sB(smem, 0); sB(smem, 1); sB(smem, 2); sB(smem, 3);
  sA(smem, 0); sA(smem, 2); sA(smem, 1); sA(smem, 3);
  asm volatile("s_waitcnt vmcnt(2)" ::: "memory");
  __builtin_amdgcn_sched_barrier(0);
  __builtin_amdgcn_s_barrier();
  __builtin_amdgcn_sched_barrier(0);

  short8 bfr[4][2];

#pragma unroll 1
  for (int t = 0; t < NT; ++t) {
    unsigned short* Ab = smem + (t & 1) * 32768;
    unsigned short* Bb = Ab + 16384;
    unsigned short* Nb = smem + ((t + 1) & 1) * 32768;
    const bool pf = (t + 1 < NT);

    // ---------------- phase 0: frags m0,m1 + all B ----------------
    {
      short8 afr[2][2];
#pragma unroll
      for (int nf = 0; nf < 4; ++nf) {
        int c = wn * 64 + nf * 16 + (lane & 15);
#pragma unroll
        for (int ks = 0; ks < 2; ++ks) {
          int kc = ks * 4 + (lane >> 4);
          bfr[nf][ks] = *(const short8*)(Bb + c * 64 + ((kc ^ (c & 7)) << 3));
        }
      }
#pragma unroll
      for (int m2 = 0; m2 < 2; ++m2) {
        int r = wm * 128 + m2 * 16 + (lane & 15);
#pragma unroll
        for (int ks = 0; ks < 2; ++ks) {
          int kc = ks * 4 + (lane >> 4);
          afr[m2][ks] = *(const short8*)(Ab + r * 64 + ((kc ^ (r & 7)) << 3));
        }
      }
      if (pf) { sB(Nb, 0); sB(Nb, 1); }
      __builtin_amdgcn_sched_barrier(0);
      __builtin_amdgcn_s_barrier();
      __builtin_amdgcn_sched_barrier(0);
      asm volatile("s_waitcnt lgkmcnt(0)" ::: "memory");
      __builtin_amdgcn_sched_barrier(0);
      __builtin_amdgcn_s_setprio(1);
#pragma unroll
      for (int m2 = 0; m2 < 2; ++m2)
#pragma unroll
        for (int nf = 0; nf < 4; ++nf)
#pragma unroll
          for (int ks = 0; ks < 2; ++ks)
            acc[m2][nf] = __builtin_amdgcn_mfma_f32_16x16x32_bf16(
                afr[m2][ks], bfr[nf][ks], acc[m2][nf], 0, 0, 0);
      __builtin_amdgcn_s_setprio(0);
    }
    // ---------------- phase 1: frags m2,m3 ----------------
    {
      short8 afr[2][2];
#pragma unroll
      for (int m2 = 0; m2 < 2; ++m2) {
        int r = wm * 128 + (2 + m2) * 16 + (lane & 15);
#pragma unroll
        for (int ks = 0; ks < 2; ++ks) {
          int kc = ks * 4 + (lane >> 4);
          afr[m2][ks] = *(const short8*)(Ab + r * 64 + ((kc ^ (r & 7)) << 3));
        }
      }
      if (pf) { sB(Nb, 2); sB(Nb, 3); }
      if (pf) { asm volatile("s_waitcnt vmcnt(4)" ::: "memory"); }
      else    { asm volatile("s_waitcnt vmcnt(0)" ::: "memory"); }
      __builtin_amdgcn_sched_barrier(0);
      __builtin_amdgcn_s_barrier();
      __builtin_amdgcn_sched_barrier(0);
      asm volatile("s_waitcnt lgkmcnt(0)" ::: "memory");
      __builtin_amdgcn_sched_barrier(0);
      __builtin_amdgcn_s_setprio(1);
#pragma unroll
      for (int m2 = 0; m2 < 2; ++m2)
#pragma unroll
        for (int nf = 0; nf < 4; ++nf)
#pragma unroll
          for (int ks = 0; ks < 2; ++ks)
            acc[2 + m2][nf] = __builtin_amdgcn_mfma_f32_16x16x32_bf16(
                afr[m2][ks], bfr[nf][ks], acc[2 + m2][nf], 0, 0, 0);
      __builtin_amdgcn_s_setprio(0);
    }
    // ---------------- phase 2: frags m4,m5 ----------------
    {
      short8 afr[2][2];
#pragma unroll
      for (int m2 = 0; m2 < 2; ++m2) {
        int r = wm * 128 + (4 + m2) * 16 + (lane & 15);
#pragma unroll
        for (int ks = 0; ks < 2; ++ks) {
          int kc = ks * 4 + (lane >> 4);
          afr[m2][ks] = *(const short8*)(Ab + r * 64 + ((kc ^ (r & 7)) << 3));
        }
      }
      if (pf) { sA(Nb, 0); sA(Nb, 2); }
      __builtin_amdgcn_sched_barrier(0);
      __builtin_amdgcn_s_barrier();
      __builtin_amdgcn_sched_barrier(0);
      asm volatile("s_waitcnt lgkmcnt(0)" ::: "memory");
      __builtin_amdgcn_sched_barrier(0);
      __builtin_amdgcn_s_setprio(1);
#pragma unroll
      for (int m2 = 0; m2 < 2; ++m2)
#pragma unroll
        for (int nf = 0; nf < 4; ++nf)
#pragma unroll
          for (int ks = 0; ks < 2; ++ks)
            acc[4 + m2][nf] = __builtin_amdgcn_mfma_f32_16x16x32_bf16(
                afr[m2][ks], bfr[nf][ks], acc[4 + m2][nf], 0, 0, 0);
      __builtin_amdgcn_s_setprio(0);
    }
    // ---------------- phase 3: frags m6,m7 ----------------
    {
      short8 afr[2][2];
#pragma unroll
      for (int m2 = 0; m2 < 2; ++m2) {
        int r = wm * 128 + (6 + m2) * 16 + (lane & 15);
#pragma unroll
        for (int ks = 0; ks < 2; ++ks) {
          int kc = ks * 4 + (lane >> 4);
          afr[m2][ks] = *(const short8*)(Ab + r * 64 + ((kc ^ (r & 7)) << 3));
        }
      }
      if (pf) { sA(Nb, 1); sA(Nb, 3); }
      if (pf) { asm volatile("s_waitcnt vmcnt(2)" ::: "memory"); }
      __builtin_amdgcn_sched_barrier(0);
      __builtin_amdgcn_s_barrier();
      __builtin_amdgcn_sched_barrier(0);
      asm volatile("s_waitcnt lgkmcnt(0)" ::: "memory");
      __builtin_amdgcn_sched_barrier(0);
      __builtin_amdgcn_s_setprio(1);
#pragma unroll
      for (int m2 = 0; m2 < 2; ++m2)
#pragma unroll
        for (int nf = 0; nf < 4; ++nf)
#pragma unroll
          for (int ks = 0; ks < 2; ++ks)
            acc[6 + m2][nf] = __builtin_amdgcn_mfma_f32_16x16x32_bf16(
                afr[m2][ks], bfr[nf][ks], acc[6 + m2][nf], 0, 0, 0);
      __builtin_amdgcn_s_setprio(0);
    }
  }

  // ---- epilogue: bias + relu + bf16 store ----
  const float* bs = bias + f * NH;
#pragma unroll
  for (int nf = 0; nf < 4; ++nf) {
    int col = n0 + wn * 64 + nf * 16 + (lane & 15);
    float bvv = bs[col];
#pragma unroll
    for (int mf = 0; mf < 8; ++mf) {
      int rbase = wm * 128 + mf * 16 + ((lane >> 4) << 2);
#pragma unroll
      for (int i = 0; i < 4; ++i) {
        int pos = m0 + rbase + i;
        if (pos < cntf) {
          float v = fmaxf(acc[mf][nf][i] + bvv, 0.0f);
          Hout[(size_t)(goff + pos) * NH + col] = f2bf(v);
        }
      }
    }
  }
}

// ------ layer-3 GEMM: depth-2 counted-vmcnt 128x64 (rowlist scatter epilogue) ------
__launch_bounds__(256, 2)
__global__ void mlp_gemm3(const unsigned short* __restrict__ Abase,
                          const unsigned short* __restrict__ Wt,
                          const float* __restrict__ bias,
                          float* __restrict__ Out,
                          const int* __restrict__ cnt,
                          const int* __restrict__ rowlist) {
  constexpr int K = NH;
  constexpr int NKT = K / 64;

  const int wg = xcd_chunk(blockIdx.x, MTILES);
  const int ty = wg;

  int f = -1, m0 = 0, goff = 0, cntf = 0;
  {
    int acc = 0, off = 0;
#pragma unroll
    for (int i = 0; i < NFAC; ++i) {
      int c = cnt[i];
      int t = (c + 127) >> 7;
      if (f < 0 && ty < acc + t) { f = i; m0 = (ty - acc) * 128; goff = off; cntf = c; }
      acc += t; off += c;
    }
  }
  if (f < 0) return;

  __shared__ unsigned short As[2][128 * 64];
  __shared__ unsigned short Bs[2][64 * 64];

  const int tid = threadIdx.x;
  const int wid = tid >> 6, lane = tid & 63;

  const int rl = lane >> 3;
  const int chs = (lane & 7) ^ rl;
  const unsigned short* pA[4];
  const unsigned short* pB[2];
  {
    const unsigned short* Aorg = Abase + (size_t)(goff + m0) * K;
    const unsigned short* Borg = Wt + (size_t)f * NC * K;
#pragma unroll
    for (int i = 0; i < 4; ++i)
      pA[i] = Aorg + (size_t)(wid * 32 + i * 8 + rl) * K + chs * 8;
#pragma unroll
    for (int i = 0; i < 2; ++i)
      pB[i] = Borg + (size_t)(wid * 16 + i * 8 + rl) * K + chs * 8;
  }

  f32x4 acc[2][4];
#pragma unroll
  for (int a = 0; a < 2; ++a)
#pragma unroll
    for (int b = 0; b < 4; ++b) acc[a][b] = (f32x4){0.f, 0.f, 0.f, 0.f};

  auto stage = [&](int buf) {
#pragma unroll
    for (int i = 0; i < 4; ++i) {
      gl_lds16(pA[i], &As[buf][(wid * 32 + i * 8) * 64]);
      pA[i] += 64;
    }
#pragma unroll
    for (int i = 0; i < 2; ++i) {
      gl_lds16(pB[i], &Bs[buf][(wid * 16 + i * 8) * 64]);
      pB[i] += 64;
    }
  };

  auto compute = [&](int buf) {
#pragma unroll
    for (int ks = 0; ks < 2; ++ks) {
      const int kc8 = ks * 4 + (lane >> 4);
      short8 av[2], bv[4];
#pragma unroll
      for (int mf = 0; mf < 2; ++mf) {
        int row = wid * 32 + mf * 16 + (lane & 15);
        av[mf] = *(const short8*)(&As[buf][0] + row * 64 + ((kc8 ^ (row & 7)) << 3));
      }
#pragma unroll
      for (int nf = 0; nf < 4; ++nf) {
        int col = nf * 16 + (lane & 15);
        bv[nf] = *(const short8*)(&Bs[buf][0] + col * 64 + ((kc8 ^ (col & 7)) << 3));
      }
      __builtin_amdgcn_s_setprio(1);
#pragma unroll
      for (int mf = 0; mf < 2; ++mf)
#pragma unroll
        for (int nf = 0; nf < 4; ++nf)
          acc[mf][nf] = __builtin_amdgcn_mfma_f32_16x16x32_bf16(
              av[mf], bv[nf], acc[mf][nf], 0, 0, 0);
      __builtin_amdgcn_s_setprio(0);
    }
  };

  stage(0);
  stage(1);
#pragma unroll 1
  for (int kt = 0; kt < NKT; ++kt) {
    if (kt < NKT - 1) { asm volatile("s_waitcnt vmcnt(6)" ::: "memory"); }
    else              { asm volatile("s_waitcnt vmcnt(0)" ::: "memory"); }
    __builtin_amdgcn_sched_barrier(0);
    __builtin_amdgcn_s_barrier();
    __builtin_amdgcn_sched_barrier(0);
    compute(kt & 1);
    __builtin_amdgcn_sched_barrier(0);
    __builtin_amdgcn_s_barrier();
    __builtin_amdgcn_sched_barrier(0);
    if (kt + 2 < NKT) stage(kt & 1);
  }

  const float* bs = bias + f * NC;
#pragma unroll
  for (int nf = 0; nf < 4; ++nf) {
    int col = nf * 16 + (lane & 15);
    float bvv = bs[col];
#pragma unroll
    for (int mf = 0; mf < 2; ++mf) {
      int rbase = wid * 32 + mf * 16 + ((lane >> 4) << 2);
#pragma unroll
      for (int i = 0; i < 4; ++i) {
        int pos = m0 + rbase + i;
        if (pos < cntf) {
          int b = rowlist[f * BB + pos];
          Out[(size_t)b * NC + col] = acc[mf][nf][i] + bvv;
        }
      }
    }
  }
}

extern "C" void kernel_launch(void* const* d_in, const int* in_sizes, int n_in,
                              void* d_out, int out_size, void* d_ws, size_t ws_size,
                              hipStream_t stream) {
  const float* graph = (const float*)d_in[0];
  const float* state = (const float*)d_in[1];
  const float* nexts = (const float*)d_in[2];
  const float* W1 = (const float*)d_in[3];
  const float* b1 = (const float*)d_in[4];
  const float* W2 = (const float*)d_in[5];
  const float* b2 = (const float*)d_in[6];
  const float* W3 = (const float*)d_in[7];
  const float* b3 = (const float*)d_in[8];
  float* out = (float*)d_out;
  char* ws = (char*)d_ws;

  const size_t ROWCAP = BB + 256;
  const size_t OFF_ROW = 256;
  const size_t OFF_W1T = OFF_ROW + (size_t)NFAC * BB * 4;
  const size_t OFF_W2T = OFF_W1T + (size_t)NFAC * NH * KP1 * 2;
  const size_t OFF_W3T = OFF_W2T + (size_t)NFAC * NH * NH * 2;
  const size_t OFF_H1  = OFF_W3T + (size_t)NFAC * NC * NH * 2;
  const size_t OFF_XG  = OFF_H1 + ROWCAP * NH * 2;

  int* cnt = (int*)ws;
  int* rowlist = (int*)(ws + OFF_ROW);
  unsigned short* w1t = (unsigned short*)(ws + OFF_W1T);
  unsigned short* w2t = (unsigned short*)(ws + OFF_W2T);
  unsigned short* w3t = (unsigned short*)(ws + OFF_W3T);
  unsigned short* h1  = (unsigned short*)(ws + OFF_H1);
  unsigned short* xg  = (unsigned short*)(ws + OFF_XG);
  unsigned short* h2  = xg;  // reuse: xg dead after layer 1

  hipFuncSetAttribute(reinterpret_cast<const void*>(mlp_gemm8p<1>),
                      hipFuncAttributeMaxDynamicSharedMemorySize, 131072);
  hipFuncSetAttribute(reinterpret_cast<const void*>(mlp_gemm8p<2>),
                      hipFuncAttributeMaxDynamicSharedMemorySize, 131072);

  hipMemsetAsync(cnt, 0, 64, stream);
  hipMemsetAsync(d_out, 0, (size_t)out_size * sizeof(float), stream);

  bucket_kernel<<<BB / 256, 256, 0, stream>>>(graph, cnt, rowlist);
  gather_x<<<BB / 4, 256, 0, stream>>>(graph, state, nexts, cnt, rowlist, xg);
  transpose_all<<<dim3(16, 20, 24), 256, 0, stream>>>(W1, W2, W3, w1t, w2t, w3t);

  mlp_gemm8p<1><<<MT256 * 4, 512, 131072, stream>>>(xg, w1t, b1, h1, cnt);
  mlp_gemm8p<2><<<MT256 * 4, 512, 131072, stream>>>(h1, w2t, b2, h2, cnt);
  mlp_gemm3<<<MTILES, 256, 0, stream>>>(h2, w3t, b3, out, cnt, rowlist);
}

// Round 13
// 237.083 us; speedup vs baseline: 1.1637x; 1.1145x over previous
//
#include <hip/hip_runtime.h>

#define BB   16384
#define GENC 216
#define OBS  512
#define NH   1024
#define NC   64
#define NFAC 8
#define NIN  1240
#define KP1  1280   // layer-1 K padded to multiple of 128
#define MTILES 136  // worst-case sum ceil(cnt_f/128)
#define MT64  264   // worst-case sum ceil(cnt_f/64)

typedef __attribute__((ext_vector_type(4))) float f32x4;
typedef __attribute__((ext_vector_type(8))) short short8;
typedef __attribute__((ext_vector_type(4))) short short4v;

__device__ __forceinline__ unsigned short f2bf(float f) {
  union { float f; unsigned u; } x; x.f = f;
  unsigned r = x.u + 0x7fffu + ((x.u >> 16) & 1u);
  return (unsigned short)(r >> 16);
}

__device__ __forceinline__ void gl_lds16(const unsigned short* g, unsigned short* l) {
  __builtin_amdgcn_global_load_lds(
      (const __attribute__((address_space(1))) void*)g,
      (__attribute__((address_space(3))) void*)l, 16, 0, 0);
}

// bijective XCD-chunked swizzle (m204)
__device__ __forceinline__ int xcd_chunk(int gid, int nwg) {
  int q = nwg >> 3, r = nwg & 7, x = gid & 7, p = gid >> 3;
  return (x < r ? x * (q + 1) : r * (q + 1) + (x - r) * q) + p;
}

// ---------- bucket: per-row last-active factor, LDS-aggregated atomics ----------
__global__ void bucket_kernel(const float* __restrict__ graph,
                              int* __restrict__ cnt, int* __restrict__ rowlist) {
  __shared__ int lcnt[NFAC];
  __shared__ int lbase[NFAC];
  int tid = threadIdx.x;
  if (tid < NFAC) lcnt[tid] = 0;
  __syncthreads();
  int b = blockIdx.x * 256 + tid;
  const float* g = graph + (size_t)b * GENC;
  float4 g0 = *(const float4*)g;
  float4 g1 = *(const float4*)(g + 4);
  int f = -1;
  if (g0.x == 1.f) f = 0;
  if (g0.y == 1.f) f = 1;
  if (g0.z == 1.f) f = 2;
  if (g0.w == 1.f) f = 3;
  if (g1.x == 1.f) f = 4;
  if (g1.y == 1.f) f = 5;
  if (g1.z == 1.f) f = 6;
  if (g1.w == 1.f) f = 7;
  int li = 0;
  if (f >= 0) li = atomicAdd(&lcnt[f], 1);
  __syncthreads();
  if (tid < NFAC) lbase[tid] = lcnt[tid] ? atomicAdd(&cnt[tid], lcnt[tid]) : 0;
  __syncthreads();
  if (f >= 0) rowlist[f * BB + lbase[f] + li] = b;
}

// ---- fused prep: blocks [0,4096) gather rows; blocks [4096,11776) transpose W ----
__global__ void prep_kernel(const float* __restrict__ graph,
                            const float* __restrict__ state,
                            const float* __restrict__ nexts,
                            const int* __restrict__ cnt,
                            const int* __restrict__ rowlist,
                            unsigned short* __restrict__ xg,
                            const float* __restrict__ W1,
                            const float* __restrict__ W2,
                            const float* __restrict__ W3,
                            unsigned short* __restrict__ w1t,
                            unsigned short* __restrict__ w2t,
                            unsigned short* __restrict__ w3t) {
  __shared__ unsigned short tile[64][65];
  const int blk = blockIdx.x;
  if (blk < 4096) {
    // ---- gather active rows, concat + f32->bf16, pad K to 1280 ----
    int w = threadIdx.x >> 6, lane = threadIdx.x & 63;
    int pos = blk * 4 + w;
    int f = -1, loc = 0, acc = 0;
#pragma unroll
    for (int i = 0; i < NFAC; ++i) {
      int c = cnt[i];
      if (f < 0 && pos < acc + c) { f = i; loc = pos - acc; }
      acc += c;
    }
    if (f < 0) return;
    int b = rowlist[f * BB + loc];
    unsigned short* dst = xg + (size_t)pos * KP1;
#pragma unroll
    for (int it = 0; it < 5; ++it) {
      int c = it * 64 + lane;
      float4 v;
      if (c < 54)       v = *(const float4*)(graph + (size_t)b * GENC + c * 4);
      else if (c < 182) v = *(const float4*)(state + (size_t)b * OBS + (c - 54) * 4);
      else if (c < 310) v = *(const float4*)(nexts + (size_t)b * OBS + (c - 182) * 4);
      else              v = make_float4(0.f, 0.f, 0.f, 0.f);
      short4v s;
      s[0] = (short)f2bf(v.x); s[1] = (short)f2bf(v.y);
      s[2] = (short)f2bf(v.z); s[3] = (short)f2bf(v.w);
      *(short4v*)(dst + c * 4) = s;
    }
  } else {
    // ---- transpose+convert: f32 [F][K][N] -> bf16 [F][N][KPad] ----
    int t = blk - 4096;                 // 16 x 20 x 24 linearized
    int x = t & 15, y = (t >> 4) % 20, z = t / 320;
    const float* src; unsigned short* dst; int K, N, KPad;
    if (z < 8)        { src = W1 + (size_t)z * NIN * NH;       dst = w1t + (size_t)z * NH * KP1;       K = NIN; N = NH; KPad = KP1; }
    else if (z < 16)  { src = W2 + (size_t)(z - 8) * NH * NH;  dst = w2t + (size_t)(z - 8) * NH * NH;  K = NH;  N = NH; KPad = NH; }
    else              { src = W3 + (size_t)(z - 16) * NH * NC; dst = w3t + (size_t)(z - 16) * NC * NH; K = NH;  N = NC; KPad = NH; }
    int k0 = y * 64, n0 = x * 64;
    if (k0 >= KPad || n0 >= N) return;
    int tr = threadIdx.x >> 6, tc = threadIdx.x & 63;
#pragma unroll
    for (int i = 0; i < 16; ++i) {
      int r = i * 4 + tr;
      int k = k0 + r;
      float v = (k < K) ? src[(size_t)k * N + n0 + tc] : 0.0f;
      tile[r][tc] = f2bf(v);
    }
    __syncthreads();
    int kp = threadIdx.x & 31, nb = threadIdx.x >> 5;
#pragma unroll
    for (int i = 0; i < 8; ++i) {
      int n = i * 8 + nb;
      union { short2 s2; unsigned u; } v;
      v.s2.x = (short)tile[kp * 2][n];
      v.s2.y = (short)tile[kp * 2 + 1][n];
      *(unsigned*)(dst + (size_t)(n0 + n) * KPad + k0 + kp * 2) = v.u;
    }
  }
}

// ====== L1/L2 GEMM: R5 structure, BK=128 (half the drain events) ======
// 128x128 tile, 4 waves (2Mx2N), 64x64 out/wave, stage->sync->4x(16 MFMA)->sync.
template <int LAYER>
__launch_bounds__(256, 2)
__global__ void mlp_gemm(const unsigned short* __restrict__ Abase,
                         const unsigned short* __restrict__ Wt,
                         const float* __restrict__ bias,
                         unsigned short* __restrict__ Hout,
                         const int* __restrict__ cnt) {
  constexpr int K   = (LAYER == 1) ? KP1 : NH;
  constexpr int NKT = K / 128;
  constexpr int NB  = NH / 128;  // 8 n-blocks

  const int wg = xcd_chunk(blockIdx.x, MTILES * NB);
  const int ty = wg / NB;          // m-tile; n fastest (A-panel L2 reuse)
  const int n0 = (wg % NB) * 128;

  int f = -1, m0 = 0, goff = 0, cntf = 0;
  {
    int acc = 0, off = 0;
#pragma unroll
    for (int i = 0; i < NFAC; ++i) {
      int c = cnt[i];
      int t = (c + 127) >> 7;
      if (f < 0 && ty < acc + t) { f = i; m0 = (ty - acc) * 128; goff = off; cntf = c; }
      acc += t; off += c;
    }
  }
  if (f < 0) return;

  __shared__ unsigned short As[128 * 128];  // 32 KB
  __shared__ unsigned short Bs[128 * 128];  // 32 KB

  const int tid = threadIdx.x, wid = tid >> 6, lane = tid & 63;
  const int wm = wid >> 1, wn = wid & 1;

  // staging: linear LDS dest (tid*16B), source chunk pre-swizzled by row&15
  const int sr = tid >> 4;              // row 0..15 within a 16-row unit
  const int chs = (tid & 15) ^ sr;      // swizzled 16B chunk (16 chunks/row)
  const unsigned short* pa = Abase + (size_t)(goff + m0 + sr) * K + chs * 8;
  const unsigned short* pb = Wt + (size_t)f * NH * K + (size_t)(n0 + sr) * K + chs * 8;

  f32x4 acc[4][4];
#pragma unroll
  for (int a = 0; a < 4; ++a)
#pragma unroll
    for (int b = 0; b < 4; ++b) acc[a][b] = (f32x4){0.f, 0.f, 0.f, 0.f};

  for (int kt = 0; kt < NKT; ++kt) {
#pragma unroll
    for (int i = 0; i < 8; ++i)
      gl_lds16(pa + (size_t)i * 16 * K, As + i * 2048 + tid * 8);
#pragma unroll
    for (int i = 0; i < 8; ++i)
      gl_lds16(pb + (size_t)i * 16 * K, Bs + i * 2048 + tid * 8);
    pa += 128; pb += 128;
    __syncthreads();   // drains vmcnt(0): tile resident
#pragma unroll
    for (int ks = 0; ks < 4; ++ks) {
      const int kc = ks * 4 + (lane >> 4);  // logical 8-elem chunk 0..15
      short8 av[4], bv[4];
#pragma unroll
      for (int mf = 0; mf < 4; ++mf) {
        int row = wm * 64 + mf * 16 + (lane & 15);
        av[mf] = *(const short8*)(As + row * 128 + ((kc ^ (row & 15)) << 3));
      }
#pragma unroll
      for (int nf = 0; nf < 4; ++nf) {
        int col = wn * 64 + nf * 16 + (lane & 15);
        bv[nf] = *(const short8*)(Bs + col * 128 + ((kc ^ (col & 15)) << 3));
      }
#pragma unroll
      for (int mf = 0; mf < 4; ++mf)
#pragma unroll
        for (int nf = 0; nf < 4; ++nf)
          acc[mf][nf] = __builtin_amdgcn_mfma_f32_16x16x32_bf16(
              av[mf], bv[nf], acc[mf][nf], 0, 0, 0);
    }
    __syncthreads();   // WAR: all reads done before next stage
  }

  // ---- epilogue: bias + relu + bf16 store ----
  const float* bs = bias + f * NH;
#pragma unroll
  for (int nf = 0; nf < 4; ++nf) {
    int col = n0 + wn * 64 + nf * 16 + (lane & 15);
    float bvv = bs[col];
#pragma unroll
    for (int mf = 0; mf < 4; ++mf) {
      int rbase = wm * 64 + mf * 16 + ((lane >> 4) << 2);
#pragma unroll
      for (int i = 0; i < 4; ++i) {
        int pos = m0 + rbase + i;
        if (pos < cntf) {
          float v = fmaxf(acc[mf][nf][i] + bvv, 0.0f);
          Hout[(size_t)(goff + pos) * NH + col] = f2bf(v);
        }
      }
    }
  }
}

// ------ L3 GEMM: BM=64 (264 blocks), depth-2 counted-vmcnt, rowlist scatter ------
__launch_bounds__(256, 2)
__global__ void mlp_gemm3(const unsigned short* __restrict__ Abase,
                          const unsigned short* __restrict__ Wt,
                          const float* __restrict__ bias,
                          float* __restrict__ Out,
                          const int* __restrict__ cnt,
                          const int* __restrict__ rowlist) {
  constexpr int K = NH;
  constexpr int NKT = K / 64;

  const int ty = xcd_chunk(blockIdx.x, MT64);

  int f = -1, m0 = 0, goff = 0, cntf = 0;
  {
    int acc = 0, off = 0;
#pragma unroll
    for (int i = 0; i < NFAC; ++i) {
      int c = cnt[i];
      int t = (c + 63) >> 6;
      if (f < 0 && ty < acc + t) { f = i; m0 = (ty - acc) * 64; goff = off; cntf = c; }
      acc += t; off += c;
    }
  }
  if (f < 0) return;

  __shared__ unsigned short As[2][64 * 64];
  __shared__ unsigned short Bs[2][64 * 64];

  const int tid = threadIdx.x;
  const int wid = tid >> 6, lane = tid & 63;

  // staging: 32-row units, linear dest, swizzled source chunk (8 chunks/row)
  const int sr = tid >> 3;             // row 0..31
  const int chs = (tid & 7) ^ (sr & 7);
  const unsigned short* pA = Abase + (size_t)(goff + m0 + sr) * K + chs * 8;
  const unsigned short* pB = Wt + (size_t)f * NC * K + (size_t)sr * K + chs * 8;

  f32x4 acc[4];
#pragma unroll
  for (int b = 0; b < 4; ++b) acc[b] = (f32x4){0.f, 0.f, 0.f, 0.f};

  auto stage = [&](int buf) {
#pragma unroll
    for (int i = 0; i < 2; ++i) gl_lds16(pA + (size_t)i * 32 * K, &As[buf][i * 2048 + tid * 8]);
#pragma unroll
    for (int i = 0; i < 2; ++i) gl_lds16(pB + (size_t)i * 32 * K, &Bs[buf][i * 2048 + tid * 8]);
    pA += 64; pB += 64;
  };

  auto compute = [&](int buf) {
#pragma unroll
    for (int ks = 0; ks < 2; ++ks) {
      const int kc = ks * 4 + (lane >> 4);  // 0..7
      int row = wid * 16 + (lane & 15);
      short8 av = *(const short8*)(&As[buf][0] + row * 64 + ((kc ^ (row & 7)) << 3));
      short8 bv[4];
#pragma unroll
      for (int nf = 0; nf < 4; ++nf) {
        int col = nf * 16 + (lane & 15);
        bv[nf] = *(const short8*)(&Bs[buf][0] + col * 64 + ((kc ^ (col & 7)) << 3));
      }
#pragma unroll
      for (int nf = 0; nf < 4; ++nf)
        acc[nf] = __builtin_amdgcn_mfma_f32_16x16x32_bf16(av, bv[nf], acc[nf], 0, 0, 0);
    }
  };

  stage(0);
  stage(1);
#pragma unroll 1
  for (int kt = 0; kt < NKT; ++kt) {
    if (kt < NKT - 1) { asm volatile("s_waitcnt vmcnt(4)" ::: "memory"); }
    else              { asm volatile("s_waitcnt vmcnt(0)" ::: "memory"); }
    __builtin_amdgcn_sched_barrier(0);
    __builtin_amdgcn_s_barrier();
    __builtin_amdgcn_sched_barrier(0);
    compute(kt & 1);
    __builtin_amdgcn_sched_barrier(0);
    __builtin_amdgcn_s_barrier();
    __builtin_amdgcn_sched_barrier(0);
    if (kt + 2 < NKT) stage(kt & 1);
  }

  const float* bs = bias + f * NC;
#pragma unroll
  for (int nf = 0; nf < 4; ++nf) {
    int col = nf * 16 + (lane & 15);
    float bvv = bs[col];
    int rbase = wid * 16 + ((lane >> 4) << 2);
#pragma unroll
    for (int i = 0; i < 4; ++i) {
      int pos = m0 + rbase + i;
      if (pos < cntf) {
        int b = rowlist[f * BB + pos];
        Out[(size_t)b * NC + col] = acc[nf][i] + bvv;
      }
    }
  }
}

extern "C" void kernel_launch(void* const* d_in, const int* in_sizes, int n_in,
                              void* d_out, int out_size, void* d_ws, size_t ws_size,
                              hipStream_t stream) {
  const float* graph = (const float*)d_in[0];
  const float* state = (const float*)d_in[1];
  const float* nexts = (const float*)d_in[2];
  const float* W1 = (const float*)d_in[3];
  const float* b1 = (const float*)d_in[4];
  const float* W2 = (const float*)d_in[5];
  const float* b2 = (const float*)d_in[6];
  const float* W3 = (const float*)d_in[7];
  const float* b3 = (const float*)d_in[8];
  float* out = (float*)d_out;
  char* ws = (char*)d_ws;

  const size_t ROWCAP = BB + 256;
  const size_t OFF_ROW = 256;
  const size_t OFF_W1T = OFF_ROW + (size_t)NFAC * BB * 4;
  const size_t OFF_W2T = OFF_W1T + (size_t)NFAC * NH * KP1 * 2;
  const size_t OFF_W3T = OFF_W2T + (size_t)NFAC * NH * NH * 2;
  const size_t OFF_H1  = OFF_W3T + (size_t)NFAC * NC * NH * 2;
  const size_t OFF_XG  = OFF_H1 + ROWCAP * NH * 2;

  int* cnt = (int*)ws;
  int* rowlist = (int*)(ws + OFF_ROW);
  unsigned short* w1t = (unsigned short*)(ws + OFF_W1T);
  unsigned short* w2t = (unsigned short*)(ws + OFF_W2T);
  unsigned short* w3t = (unsigned short*)(ws + OFF_W3T);
  unsigned short* h1  = (unsigned short*)(ws + OFF_H1);
  unsigned short* xg  = (unsigned short*)(ws + OFF_XG);
  unsigned short* h2  = xg;  // reuse: xg dead after layer 1

  hipMemsetAsync(cnt, 0, 64, stream);
  hipMemsetAsync(d_out, 0, (size_t)out_size * sizeof(float), stream);

  bucket_kernel<<<BB / 256, 256, 0, stream>>>(graph, cnt, rowlist);
  prep_kernel<<<4096 + 7680, 256, 0, stream>>>(graph, state, nexts, cnt, rowlist,
                                               xg, W1, W2, W3, w1t, w2t, w3t);

  mlp_gemm<1><<<MTILES * 8, 256, 0, stream>>>(xg, w1t, b1, h1, cnt);
  mlp_gemm<2><<<MTILES * 8, 256, 0, stream>>>(h1, w2t, b2, h2, cnt);
  mlp_gemm3<<<MT64, 256, 0, stream>>>(h2, w3t, b3, out, cnt, rowlist);
}